// Round 2
// baseline (574.246 us; speedup 1.0000x reference)
//
#include <hip/hip_runtime.h>
#include <hip/hip_bf16.h>

// Eikonal3D: 64^3 grid, 128 Jacobi sweeps of Godunov upwind update, then
// trilinear interp at 4096 events + MSE loss.
// Round 1: k=4 temporal blocking (8^3 tiles, 16^3 halo regions in LDS,
// 512 blocks) + monotone-convergence skip flags. 32 group launches
// instead of 128 sweep launches. Exact Jacobi-128 semantics preserved.
// n_iter is fixed at 128 by setup_inputs (host must know launch count).

#define NXg 64
#define NPTS (64 * 64 * 64)
#define BIGV 1000.0f
#define PADV 10000.0f   // BIG*10 pad value
#define NEV 4096

#define TB 8            // tile cells per axis
#define HALO 4          // Jacobi iterations fused per group
#define RB 16           // region edge = TB + 2*HALO
#define ZS 20           // padded z stride in LDS (16B-aligned rows, bank spread)
#define NBLK 512        // (64/TB)^3
#define NGROUPS 32      // 128 / HALO

__device__ __forceinline__ float godunov_cell(float uc, float ax, float ay,
                                              float az, float f) {
    // exact 3-way sort (med3 idiom)
    float lo = fminf(ax, ay), hi = fmaxf(ax, ay);
    float a1 = fminf(lo, az);
    float a3 = fmaxf(hi, az);
    float a2 = fminf(fmaxf(lo, az), hi);
    float x1 = a1 + f;
    float d12 = a1 - a2;
    float d2 = 2.0f * f * f - d12 * d12;
    float x2 = 0.5f * (a1 + a2 + sqrtf(fmaxf(d2, 0.0f)));
    float s = a1 + a2 + a3;
    float q = a1 * a1 + a2 * a2 + a3 * a3;
    float d3 = s * s - 3.0f * (q - f * f);
    float x3 = (s + sqrtf(fmaxf(d3, 0.0f))) * (1.0f / 3.0f);
    float unew = (x1 <= a2) ? x1 : ((x2 <= a3) ? x2 : x3);
    return fminf(uc, unew);
}

__global__ __launch_bounds__(256) void eik_init(const float* __restrict__ vp,
                                                const float* __restrict__ st,
                                                float* __restrict__ u,
                                                float* __restrict__ fh,
                                                int* __restrict__ flags0) {
    int idx = blockIdx.x * blockDim.x + threadIdx.x;
    if (idx >= NPTS) return;
    float v = vp[idx];
    fh[idx] = 1.0f / v;   // fh = (1/vp)*H, H=1

    if (idx < NBLK) flags0[idx] = 1;   // everyone computes in group 0

    int z = idx & 63;
    int y = (idx >> 6) & 63;
    int x = idx >> 12;

    float sx = st[0], sy = st[1], sz = st[2];
    int ix0 = min(max((int)floorf(sx), 0), 62);
    int iy0 = min(max((int)floorf(sy), 0), 62);
    int iz0 = min(max((int)floorf(sz), 0), 62);
    float xs = fminf(fmaxf(sx, 0.0f), 63.0f);
    float ys = fminf(fmaxf(sy, 0.0f), 63.0f);
    float zs = fminf(fmaxf(sz, 0.0f), 63.0f);

    float val = BIGV;
    if (x >= ix0 && x <= ix0 + 1 && y >= iy0 && y <= iy0 + 1 &&
        z >= iz0 && z <= iz0 + 1) {
        float dx = xs - (float)x;
        float dy = ys - (float)y;
        float dz = zs - (float)z;
        val = sqrtf(dx * dx + dy * dy + dz * dz) / v;
    }
    u[idx] = val;
}

__global__ __launch_bounds__(256, 3) void eik_group(
    const float* __restrict__ uCur, float* __restrict__ uNext,
    const float* __restrict__ fh,
    const int* __restrict__ chPrev, int* __restrict__ chNext) {
    __shared__ float A[RB * RB * ZS];
    __shared__ float B[RB * RB * ZS];
    __shared__ float stash[TB * TB * TB];
    __shared__ int s_any;

    const int b = blockIdx.x;
    const int BX = b >> 6, BY = (b >> 3) & 7, BZ = b & 7;
    const int ox = BX * TB - HALO, oy = BY * TB - HALO, oz = BZ * TB - HALO;
    const int tid = threadIdx.x;
    const int tbase = ((BX * TB) * 64 + BY * TB) * 64 + BZ * TB;

    if (tid == 0) s_any = 0;
    __syncthreads();
    if (tid < 27) {
        int dx = tid / 9 - 1, dy = (tid / 3) % 3 - 1, dz = tid % 3 - 1;
        int nx = BX + dx, ny = BY + dy, nz = BZ + dz;
        if (nx >= 0 && nx < 8 && ny >= 0 && ny < 8 && nz >= 0 && nz < 8) {
            if (chPrev[(nx << 6) | (ny << 3) | nz]) atomicOr(&s_any, 1);
        }
    }
    __syncthreads();

    if (!s_any) {
        // nothing in our 27-neighborhood changed last group -> output == input
        for (int u = tid; u < TB * TB * 2; u += 256) {
            int c = u & 1, r = u >> 1;
            int lx = r >> 3, ly = r & 7;
            int goff = tbase + (lx * 64 + ly) * 64 + 4 * c;
            *(float4*)&uNext[goff] = *(const float4*)&uCur[goff];
        }
        if (tid == 0) chNext[b] = 0;
        return;
    }

    // ---- load 16^3 region (tile +/- HALO) into both LDS buffers ----
    for (int u = tid; u < RB * RB * 4; u += 256) {
        int c = u & 3, r = u >> 2;
        int lx = r >> 4, ly = r & 15;
        int gx = ox + lx, gy = oy + ly, gz0 = oz + 4 * c;
        int loff = (lx * RB + ly) * ZS + 4 * c;
        float4 v;
        bool xyok = (gx >= 0) & (gx < 64) & (gy >= 0) & (gy < 64);
        if (xyok && gz0 >= 0 && gz0 + 3 < 64) {
            v = *(const float4*)&uCur[(gx * 64 + gy) * 64 + gz0];
        } else {
            int gb = (gx * 64 + gy) * 64;
            v.x = (xyok && gz0 + 0 >= 0 && gz0 + 0 < 64) ? uCur[gb + gz0 + 0] : PADV;
            v.y = (xyok && gz0 + 1 >= 0 && gz0 + 1 < 64) ? uCur[gb + gz0 + 1] : PADV;
            v.z = (xyok && gz0 + 2 >= 0 && gz0 + 2 < 64) ? uCur[gb + gz0 + 2] : PADV;
            v.w = (xyok && gz0 + 3 >= 0 && gz0 + 3 < 64) ? uCur[gb + gz0 + 3] : PADV;
        }
        *(float4*)&A[loff] = v;
        *(float4*)&B[loff] = v;   // so never-written (out-of-grid) cells read PADV
    }
    __syncthreads();

    // stash original tile (local [4..11]^3) for change detection
    for (int u = tid; u < TB * TB * 2; u += 256) {
        int c = u & 1, r = u >> 1;
        int lx = r >> 3, ly = r & 7;
        int loff = ((lx + 4) * RB + (ly + 4)) * ZS + 4 + 4 * c;
        *(float4*)&stash[(lx * 8 + ly) * 8 + 4 * c] = *(const float4*)&A[loff];
    }

    // ---- 4 Jacobi iterations with shrinking cube [it+1 .. 14-it]^3 ----
    #pragma unroll
    for (int it = 0; it < HALO; ++it) {
        __syncthreads();
        const float* src = (it & 1) ? B : A;
        float* dst = (it & 1) ? A : B;
        const int s0 = it + 1, s1 = 14 - it;
        const int S = s1 - s0 + 1;
        const int units = S * S * 4;
        const int lzlo = max(s0, -oz);        // gz >= 0
        const int lzhi = min(s1, 63 - oz);    // gz <= 63
        for (int u = tid; u < units; u += 256) {
            int c = u & 3, r = u >> 2;
            int ly = s0 + (r % S), lx = s0 + (r / S);
            int zb = 4 * c;
            int rowoff = (lx * RB + ly) * ZS;
            float4 cc = *(const float4*)&src[rowoff + zb];
            float zmm = src[rowoff + zb - 1];        // rowoff >= 340, safe
            float zpp = src[rowoff + zb + 4];        // within ZS padding
            float4 xm = *(const float4*)&src[rowoff - RB * ZS + zb];
            float4 xp = *(const float4*)&src[rowoff + RB * ZS + zb];
            float4 ym = *(const float4*)&src[rowoff - ZS + zb];
            float4 yp = *(const float4*)&src[rowoff + ZS + zb];

            int gx = ox + lx, gy = oy + ly, gz0 = oz + zb;
            int cgx = min(max(gx, 0), 63), cgy = min(max(gy, 0), 63);
            int cgz = min(max(gz0, 0), 60);          // stays 16B-aligned
            float4 f4 = *(const float4*)&fh[(cgx * 64 + cgy) * 64 + cgz];

            float o0 = godunov_cell(cc.x, fminf(xm.x, xp.x), fminf(ym.x, yp.x),
                                    fminf(zmm, cc.y), f4.x);
            float o1 = godunov_cell(cc.y, fminf(xm.y, xp.y), fminf(ym.y, yp.y),
                                    fminf(cc.x, cc.z), f4.y);
            float o2 = godunov_cell(cc.z, fminf(xm.z, xp.z), fminf(ym.z, yp.z),
                                    fminf(cc.y, cc.w), f4.z);
            float o3 = godunov_cell(cc.w, fminf(xm.w, xp.w), fminf(ym.w, yp.w),
                                    fminf(cc.z, zpp), f4.w);

            bool xyin = (gx >= 0) & (gx < 64) & (gy >= 0) & (gy < 64);
            int jlo = max(lzlo - zb, 0), jhi = min(lzhi - zb, 3);
            if (xyin & (jlo == 0) & (jhi == 3)) {
                *(float4*)&dst[rowoff + zb] = make_float4(o0, o1, o2, o3);
            } else if (xyin) {
                if (jlo <= 0 && 0 <= jhi) dst[rowoff + zb + 0] = o0;
                if (jlo <= 1 && 1 <= jhi) dst[rowoff + zb + 1] = o1;
                if (jlo <= 2 && 2 <= jhi) dst[rowoff + zb + 2] = o2;
                if (jlo <= 3 && 3 <= jhi) dst[rowoff + zb + 3] = o3;
            }
        }
    }
    __syncthreads();

    // ---- write back tile (final state is in A after 4 iters) + detect change
    if (tid == 0) s_any = 0;
    __syncthreads();
    int changed = 0;
    for (int u = tid; u < TB * TB * 2; u += 256) {
        int c = u & 1, r = u >> 1;
        int lx = r >> 3, ly = r & 7;
        int loff = ((lx + 4) * RB + (ly + 4)) * ZS + 4 + 4 * c;
        float4 v = *(const float4*)&A[loff];
        float4 sv = *(const float4*)&stash[(lx * 8 + ly) * 8 + 4 * c];
        int goff = tbase + (lx * 64 + ly) * 64 + 4 * c;
        *(float4*)&uNext[goff] = v;
        if (v.x != sv.x || v.y != sv.y || v.z != sv.z || v.w != sv.w) changed = 1;
    }
    int wch = __any(changed);
    if ((tid & 63) == 0 && wch) atomicOr(&s_any, 1);
    __syncthreads();
    if (tid == 0) chNext[b] = s_any;
}

__global__ __launch_bounds__(1024) void eik_finalize(const float* __restrict__ u,
                                                     const float* __restrict__ evloc,
                                                     const float* __restrict__ evtime,
                                                     const float* __restrict__ phtime,
                                                     float* __restrict__ out) {
    __shared__ float red[16];
    int t = threadIdx.x;
    float acc = 0.0f;
    for (int i = t; i < NEV; i += 1024) {
        float x = evloc[3 * i + 0];
        float y = evloc[3 * i + 1];
        float z = evloc[3 * i + 2];
        int ix0 = min(max((int)floorf(x), 0), 62);
        int iy0 = min(max((int)floorf(y), 0), 62);
        int iz0 = min(max((int)floorf(z), 0), 62);
        float xs = fminf(fmaxf(x, 0.0f), 63.0f);
        float ys = fminf(fmaxf(y, 0.0f), 63.0f);
        float zs = fminf(fmaxf(z, 0.0f), 63.0f);
        float wx0 = xs - (float)ix0, wx1 = (float)(ix0 + 1) - xs;
        float wy0 = ys - (float)iy0, wy1 = (float)(iy0 + 1) - ys;
        float wz0 = zs - (float)iz0, wz1 = (float)(iz0 + 1) - zs;
        int base = ix0 * 4096 + iy0 * 64 + iz0;
        float c000 = u[base];
        float c100 = u[base + 4096];
        float c010 = u[base + 64];
        float c110 = u[base + 4096 + 64];
        float c001 = u[base + 1];
        float c101 = u[base + 4096 + 1];
        float c011 = u[base + 64 + 1];
        float c111 = u[base + 4096 + 64 + 1];
        float tt = c000 * wx1 * wy1 * wz1 + c100 * wx0 * wy1 * wz1
                 + c010 * wx1 * wy0 * wz1 + c110 * wx0 * wy0 * wz1
                 + c001 * wx1 * wy1 * wz0 + c101 * wx0 * wy1 * wz0
                 + c011 * wx1 * wy0 * wz0 + c111 * wx0 * wy0 * wz0;
        float at = evtime[i] + tt;
        out[i] = at;
        float d = at - phtime[i];
        acc += d * d;
    }
    #pragma unroll
    for (int off = 32; off > 0; off >>= 1) acc += __shfl_down(acc, off);
    if ((t & 63) == 0) red[t >> 6] = acc;
    __syncthreads();
    if (t < 16) {
        float v = red[t];
        #pragma unroll
        for (int off = 8; off > 0; off >>= 1) v += __shfl_down(v, off);
        if (t == 0) out[NEV] = v * (1.0f / (float)NEV);
    }
}

extern "C" void kernel_launch(void* const* d_in, const int* in_sizes, int n_in,
                              void* d_out, int out_size, void* d_ws, size_t ws_size,
                              hipStream_t stream) {
    const float* vp     = (const float*)d_in[0];
    const float* stloc  = (const float*)d_in[1];
    const float* evloc  = (const float*)d_in[2];
    const float* evtime = (const float*)d_in[3];
    const float* phtime = (const float*)d_in[4];
    float* out = (float*)d_out;

    float* w  = (float*)d_ws;
    float* uA = w;                 // 64^3
    float* uB = w + NPTS;          // 64^3
    float* fh = w + 2 * NPTS;      // 64^3
    int* flA  = (int*)(w + 3 * NPTS);
    int* flB  = flA + NBLK;

    eik_init<<<NPTS / 256, 256, 0, stream>>>(vp, stloc, uA, fh, flA);

    for (int g = 0; g < NGROUPS; ++g) {
        const float* s = (g & 1) ? uB : uA;
        float*       d = (g & 1) ? uA : uB;
        const int*  fp = (g & 1) ? flB : flA;
        int*        fn = (g & 1) ? flA : flB;
        eik_group<<<NBLK, 256, 0, stream>>>(s, d, fh, fp, fn);
    }
    // 32 groups (even) -> final field back in uA

    eik_finalize<<<1, 1024, 0, stream>>>(uA, evloc, evtime, phtime, out);
}